// Round 1
// baseline (3423.420 us; speedup 1.0000x reference)
//
#include <hip/hip_runtime.h>

#define CC 16
#define LL 8192
#define SS 8191   // L-1
#define EE 512
#define HH 256
#define MM 128
#define TOPK 30

// Block: 256 threads, 64 rows per block.
// LDS: sA 64KB (h tile, later probs[64][129]); sB 16KB (x tile, K-major).
__global__ __launch_bounds__(256, 2)
void gene_router_kernel(const float* __restrict__ x,
                        const int*   __restrict__ mask,
                        const float* __restrict__ noise,
                        const float* __restrict__ W1,
                        const float* __restrict__ b1,
                        const float* __restrict__ W2,
                        const float* __restrict__ b2,
                        float* __restrict__ out,
                        float* __restrict__ outk)
{
    __shared__ float sA[64 * 256];   // h[r][256]; later probs[r][129]
    __shared__ float sB[64 * 64];    // x tile transposed: [e_local][row]

    const int tid = threadIdx.x;
    const int c   = blockIdx.y;
    const int s0  = blockIdx.x * 64;

    const int tx = tid & 15;   // 16 col-groups
    const int ty = tid >> 4;   // 16 row-groups (4 rows each)

    // ---------------- GEMM1: h[64][256] = relu(xs @ W1 + b1) ----------------
    float acc1[4][16];
#pragma unroll
    for (int i = 0; i < 4; ++i)
#pragma unroll
        for (int q = 0; q < 16; ++q) acc1[i][q] = 0.0f;

    const int rr = tid & 63;          // staging row
    const int sq = tid >> 6;          // staging e-quarter (0..3)
    const int srow = min(s0 + rr, SS - 1);            // clamp tail row
    const float* xrow = x + ((size_t)(c * LL + srow + 1)) * EE + sq * 16;

    for (int ec = 0; ec < 8; ++ec) {
        const float4 v0 = *(const float4*)(xrow + ec * 64 + 0);
        const float4 v1 = *(const float4*)(xrow + ec * 64 + 4);
        const float4 v2 = *(const float4*)(xrow + ec * 64 + 8);
        const float4 v3 = *(const float4*)(xrow + ec * 64 + 12);
        const int e0 = sq * 16;
        sB[(e0+ 0)*64+rr]=v0.x; sB[(e0+ 1)*64+rr]=v0.y; sB[(e0+ 2)*64+rr]=v0.z; sB[(e0+ 3)*64+rr]=v0.w;
        sB[(e0+ 4)*64+rr]=v1.x; sB[(e0+ 5)*64+rr]=v1.y; sB[(e0+ 6)*64+rr]=v1.z; sB[(e0+ 7)*64+rr]=v1.w;
        sB[(e0+ 8)*64+rr]=v2.x; sB[(e0+ 9)*64+rr]=v2.y; sB[(e0+10)*64+rr]=v2.z; sB[(e0+11)*64+rr]=v2.w;
        sB[(e0+12)*64+rr]=v3.x; sB[(e0+13)*64+rr]=v3.y; sB[(e0+14)*64+rr]=v3.z; sB[(e0+15)*64+rr]=v3.w;
        __syncthreads();

        const float* W1p = W1 + (size_t)(ec * 64) * HH + tx * 16;
#pragma unroll 4
        for (int e = 0; e < 64; ++e) {
            const float4 a4 = *(const float4*)&sB[e * 64 + ty * 4];
            const float4 w0 = *(const float4*)(W1p + e * HH + 0);
            const float4 w1 = *(const float4*)(W1p + e * HH + 4);
            const float4 w2 = *(const float4*)(W1p + e * HH + 8);
            const float4 w3 = *(const float4*)(W1p + e * HH + 12);
            const float av[4]  = {a4.x, a4.y, a4.z, a4.w};
            const float wv[16] = {w0.x, w0.y, w0.z, w0.w, w1.x, w1.y, w1.z, w1.w,
                                  w2.x, w2.y, w2.z, w2.w, w3.x, w3.y, w3.z, w3.w};
#pragma unroll
            for (int i = 0; i < 4; ++i)
#pragma unroll
                for (int q = 0; q < 16; ++q)
                    acc1[i][q] = fmaf(av[i], wv[q], acc1[i][q]);
        }
        __syncthreads();
    }

    // bias + relu + store h into sA
    {
        float bv[16];
        const float4 bb0 = *(const float4*)(b1 + tx * 16 + 0);
        const float4 bb1 = *(const float4*)(b1 + tx * 16 + 4);
        const float4 bb2 = *(const float4*)(b1 + tx * 16 + 8);
        const float4 bb3 = *(const float4*)(b1 + tx * 16 + 12);
        bv[0]=bb0.x; bv[1]=bb0.y; bv[2]=bb0.z; bv[3]=bb0.w;
        bv[4]=bb1.x; bv[5]=bb1.y; bv[6]=bb1.z; bv[7]=bb1.w;
        bv[8]=bb2.x; bv[9]=bb2.y; bv[10]=bb2.z; bv[11]=bb2.w;
        bv[12]=bb3.x; bv[13]=bb3.y; bv[14]=bb3.z; bv[15]=bb3.w;
#pragma unroll
        for (int i = 0; i < 4; ++i) {
            const int r = ty * 4 + i;
#pragma unroll
            for (int g = 0; g < 4; ++g) {
                float4 hv;
                hv.x = fmaxf(acc1[i][g*4+0] + bv[g*4+0], 0.0f);
                hv.y = fmaxf(acc1[i][g*4+1] + bv[g*4+1], 0.0f);
                hv.z = fmaxf(acc1[i][g*4+2] + bv[g*4+2], 0.0f);
                hv.w = fmaxf(acc1[i][g*4+3] + bv[g*4+3], 0.0f);
                *(float4*)&sA[r * 256 + tx * 16 + g * 4] = hv;
            }
        }
    }
    __syncthreads();

    // ---------------- GEMM2: logits[64][128] = h @ W2 + b2 ----------------
    // thread: rows ty*4..+3, cols tx*8..+7
    float acc2[4][8];
#pragma unroll
    for (int i = 0; i < 4; ++i)
#pragma unroll
        for (int q = 0; q < 8; ++q) acc2[i][q] = 0.0f;

    {
        const float* W2p = W2 + tx * 8;
#pragma unroll 2
        for (int k4 = 0; k4 < 64; ++k4) {
            const float4 a0 = *(const float4*)&sA[(ty*4+0) * 256 + k4 * 4];
            const float4 a1 = *(const float4*)&sA[(ty*4+1) * 256 + k4 * 4];
            const float4 a2 = *(const float4*)&sA[(ty*4+2) * 256 + k4 * 4];
            const float4 a3 = *(const float4*)&sA[(ty*4+3) * 256 + k4 * 4];
            const float am[4][4] = {{a0.x,a0.y,a0.z,a0.w},
                                    {a1.x,a1.y,a1.z,a1.w},
                                    {a2.x,a2.y,a2.z,a2.w},
                                    {a3.x,a3.y,a3.z,a3.w}};
#pragma unroll
            for (int kk = 0; kk < 4; ++kk) {
                const float* wp = W2p + (size_t)(k4 * 4 + kk) * MM;
                const float4 w0 = *(const float4*)(wp + 0);
                const float4 w1 = *(const float4*)(wp + 4);
                const float wv[8] = {w0.x,w0.y,w0.z,w0.w,w1.x,w1.y,w1.z,w1.w};
#pragma unroll
                for (int i = 0; i < 4; ++i)
#pragma unroll
                    for (int q = 0; q < 8; ++q)
                        acc2[i][q] = fmaf(am[i][kk], wv[q], acc2[i][q]);
            }
        }
    }

    // ---------------- epilogue: gumbel + softmax ----------------
    float b2v[8];
    {
        const float4 bb0 = *(const float4*)(b2 + tx * 8 + 0);
        const float4 bb1 = *(const float4*)(b2 + tx * 8 + 4);
        b2v[0]=bb0.x; b2v[1]=bb0.y; b2v[2]=bb0.z; b2v[3]=bb0.w;
        b2v[4]=bb1.x; b2v[5]=bb1.y; b2v[6]=bb1.z; b2v[7]=bb1.w;
    }

    float pr[4][8];   // becomes probs
#pragma unroll
    for (int i = 0; i < 4; ++i) {
        const int s  = s0 + ty * 4 + i;
        const int sc = min(s, SS - 1);
        const float* np_ = noise + ((size_t)c * SS + sc) * MM + tx * 8;
        const float4 u0 = *(const float4*)(np_ + 0);
        const float4 u1 = *(const float4*)(np_ + 4);
        const float uu[8] = {u0.x,u0.y,u0.z,u0.w,u1.x,u1.y,u1.z,u1.w};
        float pm[8];
#pragma unroll
        for (int q = 0; q < 8; ++q) {
            const float g = -logf(-logf(uu[q] + 1e-20f) + 1e-20f);
            pm[q] = acc2[i][q] + b2v[q] + g;   // TEMP = TAU = 1
        }
        // row max over 128 (8 local + 16-lane group)
        float mx = pm[0];
#pragma unroll
        for (int q = 1; q < 8; ++q) mx = fmaxf(mx, pm[q]);
        for (int d = 1; d < 16; d <<= 1) mx = fmaxf(mx, __shfl_xor(mx, d, 16));
        float se = 0.0f;
#pragma unroll
        for (int q = 0; q < 8; ++q) { pr[i][q] = expf(pm[q] - mx); se += pr[i][q]; }
        for (int d = 1; d < 16; d <<= 1) se += __shfl_xor(se, d, 16);
        const float inv = 1.0f / se;
#pragma unroll
        for (int q = 0; q < 8; ++q) pr[i][q] *= inv;
    }

    // publish probs to LDS (stride 129 to avoid bank conflicts)
    __syncthreads();   // all h reads done; reuse sA
    float* probsL = sA;
#pragma unroll
    for (int i = 0; i < 4; ++i) {
        const int r = ty * 4 + i;
#pragma unroll
        for (int q = 0; q < 8; ++q) probsL[r * 129 + tx * 8 + q] = pr[i][q];
    }
    __syncthreads();

    // ---------------- top-K threshold via rank counting ----------------
    int cgt[4][8];
#pragma unroll
    for (int i = 0; i < 4; ++i)
#pragma unroll
        for (int q = 0; q < 8; ++q) cgt[i][q] = 0;

#pragma unroll 2
    for (int j = 0; j < 128; ++j) {
        const float pj0 = probsL[(ty*4+0) * 129 + j];
        const float pj1 = probsL[(ty*4+1) * 129 + j];
        const float pj2 = probsL[(ty*4+2) * 129 + j];
        const float pj3 = probsL[(ty*4+3) * 129 + j];
#pragma unroll
        for (int q = 0; q < 8; ++q) {
            cgt[0][q] += (pj0 > pr[0][q]) ? 1 : 0;
            cgt[1][q] += (pj1 > pr[1][q]) ? 1 : 0;
            cgt[2][q] += (pj2 > pr[2][q]) ? 1 : 0;
            cgt[3][q] += (pj3 > pr[3][q]) ? 1 : 0;
        }
    }

    float thr_[4];
#pragma unroll
    for (int i = 0; i < 4; ++i) {
        float t = -1.0f;
#pragma unroll
        for (int q = 0; q < 8; ++q)
            if (cgt[i][q] == TOPK - 1) t = pr[i][q];
        for (int d = 1; d < 16; d <<= 1) t = fmaxf(t, __shfl_xor(t, d, 16));
        if (t < 0.0f) {
            // rare tie-straddle fallback: need >= counts
            int cge[8];
#pragma unroll
            for (int q = 0; q < 8; ++q) cge[q] = 0;
            for (int j = 0; j < 128; ++j) {
                const float pj = probsL[(ty*4+i) * 129 + j];
#pragma unroll
                for (int q = 0; q < 8; ++q) cge[q] += (pj >= pr[i][q]) ? 1 : 0;
            }
#pragma unroll
            for (int q = 0; q < 8; ++q)
                if (cgt[i][q] <= TOPK - 1 && cge[q] >= TOPK) t = fmaxf(t, pr[i][q]);
            for (int d = 1; d < 16; d <<= 1) t = fmaxf(t, __shfl_xor(t, d, 16));
        }
        thr_[i] = t;
    }

    // ---------------- sigmoid gate + mask + store ----------------
#pragma unroll
    for (int i = 0; i < 4; ++i) {
        const int s = s0 + ty * 4 + i;
        if (s < SS) {
            const float mz = (mask[(size_t)c * LL + s + 1] != 0) ? 0.0f : 1.0f;
            float ov[8];
#pragma unroll
            for (int q = 0; q < 8; ++q) {
                const float sm = 1.0f / (1.0f + expf((thr_[i] - pr[i][q]) * 100.0f));
                ov[q] = pr[i][q] * sm * mz;
            }
            float* op = out + ((size_t)c * SS + s) * MM + tx * 8;
            float4 o0, o1;
            o0.x=ov[0]; o0.y=ov[1]; o0.z=ov[2]; o0.w=ov[3];
            o1.x=ov[4]; o1.y=ov[5]; o1.z=ov[6]; o1.w=ov[7];
            *(float4*)(op + 0) = o0;
            *(float4*)(op + 4) = o1;
        }
    }

    // kpm output (float 0/1)
    if (tid < 64) {
        const int s = s0 + tid;
        if (s < SS)
            outk[(size_t)c * SS + s] = (mask[(size_t)c * LL + s + 1] != 0) ? 1.0f : 0.0f;
    }
}

extern "C" void kernel_launch(void* const* d_in, const int* in_sizes, int n_in,
                              void* d_out, int out_size, void* d_ws, size_t ws_size,
                              hipStream_t stream) {
    const float* x     = (const float*)d_in[0];
    const int*   mask  = (const int*)d_in[1];
    const float* noise = (const float*)d_in[2];
    const float* W1    = (const float*)d_in[3];
    const float* b1    = (const float*)d_in[4];
    const float* W2    = (const float*)d_in[5];
    const float* b2    = (const float*)d_in[6];
    float* out  = (float*)d_out;
    float* outk = out + (size_t)CC * SS * MM;

    dim3 grid(128, CC);
    dim3 block(256);
    gene_router_kernel<<<grid, block, 0, stream>>>(x, mask, noise, W1, b1, W2, b2, out, outk);
}

// Round 2
// 258.480 us; speedup vs baseline: 13.2444x; 13.2444x over previous
//
#include <hip/hip_runtime.h>

#define CC 16
#define LL 8192
#define SS 8191   // L-1
#define EE 512
#define HH 256
#define MM 128
#define TOPK 30

typedef __attribute__((ext_vector_type(8))) short short8;
typedef __attribute__((ext_vector_type(4))) float f32x4;

static __device__ __forceinline__ unsigned short f2bf(float f) {
    unsigned u = __builtin_bit_cast(unsigned, f);
    u += 0x7FFFu + ((u >> 16) & 1u);   // RNE; inputs are finite normals
    return (unsigned short)(u >> 16);
}

// ---------------- prep: W1 (E x H) -> W1T bf16 (H x E); W2 (H x M) -> W2T bf16 (M x H)
__global__ void prep_weights(const float* __restrict__ W1, const float* __restrict__ W2,
                             unsigned short* __restrict__ W1T, unsigned short* __restrict__ W2T)
{
    const int b = blockIdx.x, tid = threadIdx.x;
    if (b < 64) {
        const int e0 = b * 8, h = tid;                 // 256 threads = all h
        short8 sv;
#pragma unroll
        for (int j = 0; j < 8; ++j)
            sv[j] = (short)f2bf(W1[(size_t)(e0 + j) * HH + h]);
        *(short8*)(void*)(W1T + (size_t)h * EE + e0) = sv;
    } else {
        const int h0 = (b - 64) * 16;
        if (tid < MM) {
            const int m = tid;
            short8 s0v, s1v;
#pragma unroll
            for (int j = 0; j < 8; ++j) {
                s0v[j] = (short)f2bf(W2[(size_t)(h0 + j) * MM + m]);
                s1v[j] = (short)f2bf(W2[(size_t)(h0 + 8 + j) * MM + m]);
            }
            *(short8*)(void*)(W2T + (size_t)m * HH + h0) = s0v;
            *(short8*)(void*)(W2T + (size_t)m * HH + h0 + 8) = s1v;
        }
    }
}

// ---------------- fused main kernel: 32 rows/block, 256 threads (4 waves)
__global__ __launch_bounds__(256, 3)
void gene_router_kernel(const float* __restrict__ x,
                        const int*   __restrict__ mask,
                        const float* __restrict__ noise,
                        const unsigned short* __restrict__ W1T,
                        const float* __restrict__ b1,
                        const unsigned short* __restrict__ W2T,
                        const float* __restrict__ b2,
                        float* __restrict__ out,
                        float* __restrict__ outk)
{
    __shared__ unsigned char sXraw[32 * 1024];  // xs tile bf16 swizzled [32][512]; later logits f32 [32][132]
    __shared__ unsigned char sHraw[16 * 1024];  // h tile bf16 swizzled [32][256]

    const int tid = threadIdx.x;
    const int c   = blockIdx.y;
    const int s0  = blockIdx.x * 32;

    // ---- stage x (f32 -> bf16, XOR-swizzled rows) ----
    {
        const float* xb = x + ((size_t)c * LL + s0 + 1) * EE;
#pragma unroll
        for (int it = 0; it < 8; ++it) {
            const int chunk = it * 256 + tid;
            const int row = chunk >> 6, slot = chunk & 63;
            const int rs = min(s0 + row, SS - 1) - s0;   // clamp tail row for loads
            const float* p = xb + (size_t)rs * EE + slot * 8;
            const float4 a = *(const float4*)p;
            const float4 b = *(const float4*)(p + 4);
            short8 sv;
            sv[0]=(short)f2bf(a.x); sv[1]=(short)f2bf(a.y); sv[2]=(short)f2bf(a.z); sv[3]=(short)f2bf(a.w);
            sv[4]=(short)f2bf(b.x); sv[5]=(short)f2bf(b.y); sv[6]=(short)f2bf(b.z); sv[7]=(short)f2bf(b.w);
            *(short8*)(void*)(sXraw + row * 1024 + ((slot * 16) ^ ((row & 7) << 4))) = sv;
        }
    }
    __syncthreads();

    const int w  = tid >> 6;        // wave id 0..3
    const int lane = tid & 63;
    const int lr = lane & 15;       // fragment row/col lane
    const int kq = lane >> 4;       // k-quarter 0..3

    // ---- GEMM1: h[32][256] = relu(xs @ W1 + b1), wave w -> cols w*64..+63 ----
    f32x4 acc[2][4];
#pragma unroll
    for (int r = 0; r < 2; ++r)
#pragma unroll
        for (int n = 0; n < 4; ++n) acc[r][n] = (f32x4)0.0f;

    const int cw = w * 64;
#pragma unroll 4
    for (int ks = 0; ks < 16; ++ks) {
        short8 af[2];
#pragma unroll
        for (int r = 0; r < 2; ++r) {
            const int row = r * 16 + lr;
            af[r] = *(const short8*)(const void*)(sXraw + row * 1024 + ((ks * 64 + kq * 16) ^ ((row & 7) << 4)));
        }
        short8 bf[4];
#pragma unroll
        for (int n = 0; n < 4; ++n)
            bf[n] = *(const short8*)(const void*)(W1T + (size_t)(cw + n * 16 + lr) * EE + ks * 32 + kq * 8);
#pragma unroll
        for (int r = 0; r < 2; ++r)
#pragma unroll
            for (int n = 0; n < 4; ++n)
                acc[r][n] = __builtin_amdgcn_mfma_f32_16x16x32_bf16(af[r], bf[n], acc[r][n], 0, 0, 0);
    }

    // bias + relu -> sH (bf16, swizzled)
#pragma unroll
    for (int n = 0; n < 4; ++n) {
        const int colh = cw + n * 16 + lr;
        const float bb = b1[colh];
#pragma unroll
        for (int r = 0; r < 2; ++r)
#pragma unroll
            for (int q = 0; q < 4; ++q) {
                const int row = r * 16 + kq * 4 + q;
                const unsigned short hv = f2bf(fmaxf(acc[r][n][q] + bb, 0.0f));
                *(unsigned short*)(sHraw + row * 512 + ((colh * 2) ^ ((row & 7) << 4))) = hv;
            }
    }
    __syncthreads();

    // ---- GEMM2: logits[32][128] = h @ W2, wave w -> cols w*32..+31 ----
    f32x4 acc2[2][2];
#pragma unroll
    for (int r = 0; r < 2; ++r)
#pragma unroll
        for (int n = 0; n < 2; ++n) acc2[r][n] = (f32x4)0.0f;

    const int cw2 = w * 32;
#pragma unroll 2
    for (int ks = 0; ks < 8; ++ks) {
        short8 ah[2];
#pragma unroll
        for (int r = 0; r < 2; ++r) {
            const int row = r * 16 + lr;
            ah[r] = *(const short8*)(const void*)(sHraw + row * 512 + ((ks * 64 + kq * 16) ^ ((row & 7) << 4)));
        }
        short8 bw[2];
#pragma unroll
        for (int n = 0; n < 2; ++n)
            bw[n] = *(const short8*)(const void*)(W2T + (size_t)(cw2 + n * 16 + lr) * HH + ks * 32 + kq * 8);
#pragma unroll
        for (int r = 0; r < 2; ++r)
#pragma unroll
            for (int n = 0; n < 2; ++n)
                acc2[r][n] = __builtin_amdgcn_mfma_f32_16x16x32_bf16(ah[r], bw[n], acc2[r][n], 0, 0, 0);
    }

    // logits -> sL f32 [32][132] (reuses sXraw; all sX reads finished at the h barrier)
    float* sL = (float*)sXraw;
#pragma unroll
    for (int r = 0; r < 2; ++r)
#pragma unroll
        for (int n = 0; n < 2; ++n)
#pragma unroll
            for (int q = 0; q < 4; ++q) {
                const int row = r * 16 + kq * 4 + q;
                const int col = cw2 + n * 16 + lr;
                sL[row * 132 + col] = acc2[r][n][q];
            }
    __syncthreads();

    // ---- epilogue: gumbel + softmax + top-K threshold + gate + mask ----
    const int tx = tid & 15;   // 8 consecutive cols: tx*8..+7
    const int ty = tid >> 4;   // 2 rows: ty*2, ty*2+1

    float b2v[8];
    {
        const float4 bb0 = *(const float4*)(b2 + tx * 8 + 0);
        const float4 bb1 = *(const float4*)(b2 + tx * 8 + 4);
        b2v[0]=bb0.x; b2v[1]=bb0.y; b2v[2]=bb0.z; b2v[3]=bb0.w;
        b2v[4]=bb1.x; b2v[5]=bb1.y; b2v[6]=bb1.z; b2v[7]=bb1.w;
    }

    float pr[2][8];
#pragma unroll
    for (int i = 0; i < 2; ++i) {
        const int s  = s0 + ty * 2 + i;
        const int sc = min(s, SS - 1);
        const float* np_ = noise + ((size_t)c * SS + sc) * MM + tx * 8;
        const float4 u0 = *(const float4*)(np_ + 0);
        const float4 u1 = *(const float4*)(np_ + 4);
        const float uu[8] = {u0.x,u0.y,u0.z,u0.w,u1.x,u1.y,u1.z,u1.w};
        float pm[8];
#pragma unroll
        for (int q = 0; q < 8; ++q) {
            const float g = -logf(-logf(uu[q] + 1e-20f) + 1e-20f);
            pm[q] = sL[(ty * 2 + i) * 132 + tx * 8 + q] + b2v[q] + g;
        }
        float mx = pm[0];
#pragma unroll
        for (int q = 1; q < 8; ++q) mx = fmaxf(mx, pm[q]);
        for (int d = 1; d < 16; d <<= 1) mx = fmaxf(mx, __shfl_xor(mx, d, 16));
        float se = 0.0f;
#pragma unroll
        for (int q = 0; q < 8; ++q) { pr[i][q] = expf(pm[q] - mx); se += pr[i][q]; }
        for (int d = 1; d < 16; d <<= 1) se += __shfl_xor(se, d, 16);
        const float inv = 1.0f / se;
#pragma unroll
        for (int q = 0; q < 8; ++q) pr[i][q] *= inv;
    }

    // publish probs (overwrite logits in place)
#pragma unroll
    for (int i = 0; i < 2; ++i)
#pragma unroll
        for (int q = 0; q < 8; ++q)
            sL[(ty * 2 + i) * 132 + tx * 8 + q] = pr[i][q];
    __syncthreads();

    // rank counting for top-K threshold
    int cgt[2][8];
#pragma unroll
    for (int i = 0; i < 2; ++i)
#pragma unroll
        for (int q = 0; q < 8; ++q) cgt[i][q] = 0;

#pragma unroll 2
    for (int j = 0; j < 128; ++j) {
        const float pj0 = sL[(ty * 2 + 0) * 132 + j];
        const float pj1 = sL[(ty * 2 + 1) * 132 + j];
#pragma unroll
        for (int q = 0; q < 8; ++q) {
            cgt[0][q] += (pj0 > pr[0][q]) ? 1 : 0;
            cgt[1][q] += (pj1 > pr[1][q]) ? 1 : 0;
        }
    }

    float thr_[2];
#pragma unroll
    for (int i = 0; i < 2; ++i) {
        float t = -1.0f;
#pragma unroll
        for (int q = 0; q < 8; ++q)
            if (cgt[i][q] == TOPK - 1) t = pr[i][q];
        for (int d = 1; d < 16; d <<= 1) t = fmaxf(t, __shfl_xor(t, d, 16));
        if (t < 0.0f) {
            // tie-straddle fallback
            int cge[8];
#pragma unroll
            for (int q = 0; q < 8; ++q) cge[q] = 0;
            for (int j = 0; j < 128; ++j) {
                const float pj = sL[(ty * 2 + i) * 132 + j];
#pragma unroll
                for (int q = 0; q < 8; ++q) cge[q] += (pj >= pr[i][q]) ? 1 : 0;
            }
#pragma unroll
            for (int q = 0; q < 8; ++q)
                if (cgt[i][q] <= TOPK - 1 && cge[q] >= TOPK) t = fmaxf(t, pr[i][q]);
            for (int d = 1; d < 16; d <<= 1) t = fmaxf(t, __shfl_xor(t, d, 16));
        }
        thr_[i] = t;
    }

#pragma unroll
    for (int i = 0; i < 2; ++i) {
        const int s = s0 + ty * 2 + i;
        if (s < SS) {
            const float mz = (mask[(size_t)c * LL + s + 1] != 0) ? 0.0f : 1.0f;
            float ov[8];
#pragma unroll
            for (int q = 0; q < 8; ++q) {
                const float sm = 1.0f / (1.0f + expf((thr_[i] - pr[i][q]) * 100.0f));
                ov[q] = pr[i][q] * sm * mz;
            }
            float* op = out + ((size_t)c * SS + s) * MM + tx * 8;
            float4 o0, o1;
            o0.x=ov[0]; o0.y=ov[1]; o0.z=ov[2]; o0.w=ov[3];
            o1.x=ov[4]; o1.y=ov[5]; o1.z=ov[6]; o1.w=ov[7];
            *(float4*)(op + 0) = o0;
            *(float4*)(op + 4) = o1;
        }
    }

    if (tid < 32) {
        const int s = s0 + tid;
        if (s < SS)
            outk[(size_t)c * SS + s] = (mask[(size_t)c * LL + s + 1] != 0) ? 1.0f : 0.0f;
    }
}

extern "C" void kernel_launch(void* const* d_in, const int* in_sizes, int n_in,
                              void* d_out, int out_size, void* d_ws, size_t ws_size,
                              hipStream_t stream) {
    const float* x     = (const float*)d_in[0];
    const int*   mask  = (const int*)d_in[1];
    const float* noise = (const float*)d_in[2];
    const float* W1    = (const float*)d_in[3];
    const float* b1    = (const float*)d_in[4];
    const float* W2    = (const float*)d_in[5];
    const float* b2    = (const float*)d_in[6];
    float* out  = (float*)d_out;
    float* outk = out + (size_t)CC * SS * MM;

    unsigned short* W1T = (unsigned short*)d_ws;            // 256 x 512 bf16 = 256 KB
    unsigned short* W2T = W1T + (size_t)HH * EE;            // 128 x 256 bf16 =  64 KB

    prep_weights<<<dim3(80), dim3(256), 0, stream>>>(W1, W2, W1T, W2T);

    dim3 grid(256, CC);   // 256 blocks x 32 rows = 8192 >= 8191
    gene_router_kernel<<<grid, dim3(256), 0, stream>>>(x, mask, noise, W1T, b1, W2T, b2, out, outk);
}

// Round 3
// 217.669 us; speedup vs baseline: 15.7276x; 1.1875x over previous
//
#include <hip/hip_runtime.h>

#define CC 16
#define LL 8192
#define SS 8191   // L-1
#define EE 512
#define HH 256
#define MM 128
#define TOPK 30

typedef __attribute__((ext_vector_type(8))) short short8;
typedef __attribute__((ext_vector_type(4))) float f32x4;

static __device__ __forceinline__ unsigned short f2bf(float f) {
    unsigned u = __builtin_bit_cast(unsigned, f);
    u += 0x7FFFu + ((u >> 16) & 1u);   // RNE; inputs are finite normals
    return (unsigned short)(u >> 16);
}

// ---------------- prep: W1 (E x H) -> W1T bf16 (H x E); W2 (H x M) -> W2T bf16 (M x H)
__global__ void prep_weights(const float* __restrict__ W1, const float* __restrict__ W2,
                             unsigned short* __restrict__ W1T, unsigned short* __restrict__ W2T)
{
    const int b = blockIdx.x, tid = threadIdx.x;
    if (b < 64) {
        const int e0 = b * 8, h = tid;                 // 256 threads = all h
        short8 sv;
#pragma unroll
        for (int j = 0; j < 8; ++j)
            sv[j] = (short)f2bf(W1[(size_t)(e0 + j) * HH + h]);
        *(short8*)(void*)(W1T + (size_t)h * EE + e0) = sv;
    } else {
        const int h0 = (b - 64) * 16;
        if (tid < MM) {
            const int m = tid;
            short8 s0v, s1v;
#pragma unroll
            for (int j = 0; j < 8; ++j) {
                s0v[j] = (short)f2bf(W2[(size_t)(h0 + j) * MM + m]);
                s1v[j] = (short)f2bf(W2[(size_t)(h0 + 8 + j) * MM + m]);
            }
            *(short8*)(void*)(W2T + (size_t)m * HH + h0) = s0v;
            *(short8*)(void*)(W2T + (size_t)m * HH + h0 + 8) = s1v;
        }
    }
}

// ---------------- fused main kernel: 32 rows/block, 256 threads (4 waves)
// LDS 32KB total: [0,16K) x cols 0..255 -> later h[32][256] bf16
//                 [16K,32K) x cols 256..511 -> later logits f32 [32][128]
__global__ __launch_bounds__(256, 5)
void gene_router_kernel(const float* __restrict__ x,
                        const int*   __restrict__ mask,
                        const float* __restrict__ noise,
                        const unsigned short* __restrict__ W1T,
                        const float* __restrict__ b1,
                        const unsigned short* __restrict__ W2T,
                        const float* __restrict__ b2,
                        float* __restrict__ out,
                        float* __restrict__ outk)
{
    __shared__ unsigned char lds[32 * 1024];

    const int tid = threadIdx.x;
    const int c   = blockIdx.y;
    const int s0  = blockIdx.x * 32;

    // ---- stage x (f32 -> bf16, XOR-swizzled rows, split into two 16KB halves) ----
    {
        const float* xb = x + ((size_t)c * LL + s0 + 1) * EE;
#pragma unroll
        for (int it = 0; it < 8; ++it) {
            const int chunk = it * 256 + tid;
            const int row = chunk >> 6, cc = chunk & 63;      // cc: 8-col unit
            const int half = cc >> 5, slot = cc & 31;
            const int rs = min(s0 + row, SS - 1) - s0;        // clamp tail row
            const float* p = xb + (size_t)rs * EE + cc * 8;
            const float4 a = *(const float4*)p;
            const float4 b = *(const float4*)(p + 4);
            short8 sv;
            sv[0]=(short)f2bf(a.x); sv[1]=(short)f2bf(a.y); sv[2]=(short)f2bf(a.z); sv[3]=(short)f2bf(a.w);
            sv[4]=(short)f2bf(b.x); sv[5]=(short)f2bf(b.y); sv[6]=(short)f2bf(b.z); sv[7]=(short)f2bf(b.w);
            *(short8*)(void*)(lds + half * 16384 + row * 512 + ((slot * 16) ^ ((row & 7) << 4))) = sv;
        }
    }
    __syncthreads();

    const int w  = tid >> 6;        // wave id 0..3
    const int lane = tid & 63;
    const int lr = lane & 15;       // fragment row/col lane
    const int kq = lane >> 4;       // k-quarter 0..3

    // ---- GEMM1: h[32][256] = relu(xs @ W1 + b1), wave w -> cols w*64..+63 ----
    f32x4 acc[2][4];
#pragma unroll
    for (int r = 0; r < 2; ++r)
#pragma unroll
        for (int n = 0; n < 4; ++n) acc[r][n] = (f32x4)0.0f;

    const int cw = w * 64;
#pragma unroll 4
    for (int ks = 0; ks < 16; ++ks) {
        short8 af[2];
#pragma unroll
        for (int r = 0; r < 2; ++r) {
            const int row = r * 16 + lr;
            af[r] = *(const short8*)(const void*)(lds + (ks >> 3) * 16384 + row * 512
                        + ((((ks & 7) * 64) + kq * 16) ^ ((row & 7) << 4)));
        }
        short8 bf[4];
#pragma unroll
        for (int n = 0; n < 4; ++n)
            bf[n] = *(const short8*)(const void*)(W1T + (size_t)(cw + n * 16 + lr) * EE + ks * 32 + kq * 8);
#pragma unroll
        for (int r = 0; r < 2; ++r)
#pragma unroll
            for (int n = 0; n < 4; ++n)
                acc[r][n] = __builtin_amdgcn_mfma_f32_16x16x32_bf16(af[r], bf[n], acc[r][n], 0, 0, 0);
    }
    __syncthreads();   // all sX reads done before sH overwrites half A

    // bias + relu -> sH (bf16, swizzled) in [0,16K)
#pragma unroll
    for (int n = 0; n < 4; ++n) {
        const int colh = cw + n * 16 + lr;
        const float bb = b1[colh];
#pragma unroll
        for (int r = 0; r < 2; ++r)
#pragma unroll
            for (int q = 0; q < 4; ++q) {
                const int row = r * 16 + kq * 4 + q;
                const unsigned short hv = f2bf(fmaxf(acc[r][n][q] + bb, 0.0f));
                *(unsigned short*)(lds + row * 512 + ((colh * 2) ^ ((row & 7) << 4))) = hv;
            }
    }
    __syncthreads();

    // ---- GEMM2: logits[32][128] = h @ W2, wave w -> cols w*32..+31 ----
    f32x4 acc2[2][2];
#pragma unroll
    for (int r = 0; r < 2; ++r)
#pragma unroll
        for (int n = 0; n < 2; ++n) acc2[r][n] = (f32x4)0.0f;

    const int cw2 = w * 32;
#pragma unroll 2
    for (int ks = 0; ks < 8; ++ks) {
        short8 ah[2];
#pragma unroll
        for (int r = 0; r < 2; ++r) {
            const int row = r * 16 + lr;
            ah[r] = *(const short8*)(const void*)(lds + row * 512 + ((ks * 64 + kq * 16) ^ ((row & 7) << 4)));
        }
        short8 bw[2];
#pragma unroll
        for (int n = 0; n < 2; ++n)
            bw[n] = *(const short8*)(const void*)(W2T + (size_t)(cw2 + n * 16 + lr) * HH + ks * 32 + kq * 8);
#pragma unroll
        for (int r = 0; r < 2; ++r)
#pragma unroll
            for (int n = 0; n < 2; ++n)
                acc2[r][n] = __builtin_amdgcn_mfma_f32_16x16x32_bf16(ah[r], bw[n], acc2[r][n], 0, 0, 0);
    }

    // logits -> sL f32 [32][128] in [16K,32K) (half B dead after GEMM1 barrier)
    float* sL = (float*)(lds + 16384);
#pragma unroll
    for (int r = 0; r < 2; ++r)
#pragma unroll
        for (int n = 0; n < 2; ++n)
#pragma unroll
            for (int q = 0; q < 4; ++q) {
                const int row = r * 16 + kq * 4 + q;
                const int col = cw2 + n * 16 + lr;
                sL[row * 128 + col] = acc2[r][n][q];
            }
    __syncthreads();

    // ---- epilogue: gumbel + softmax (probs stay in registers) ----
    const int tx = tid & 15;   // 8 consecutive cols: tx*8..+7
    const int ty = tid >> 4;   // 2 rows: ty*2, ty*2+1

    float b2v[8];
    {
        const float4 bb0 = *(const float4*)(b2 + tx * 8 + 0);
        const float4 bb1 = *(const float4*)(b2 + tx * 8 + 4);
        b2v[0]=bb0.x; b2v[1]=bb0.y; b2v[2]=bb0.z; b2v[3]=bb0.w;
        b2v[4]=bb1.x; b2v[5]=bb1.y; b2v[6]=bb1.z; b2v[7]=bb1.w;
    }

    float pr[2][8];
    float pmaxv[2];
#pragma unroll
    for (int i = 0; i < 2; ++i) {
        const int row = ty * 2 + i;
        const int s  = s0 + row;
        const int sc = min(s, SS - 1);
        const float* np_ = noise + ((size_t)c * SS + sc) * MM + tx * 8;
        const float4 u0 = *(const float4*)(np_ + 0);
        const float4 u1 = *(const float4*)(np_ + 4);
        const float uu[8] = {u0.x,u0.y,u0.z,u0.w,u1.x,u1.y,u1.z,u1.w};
        float pm[8];
#pragma unroll
        for (int q = 0; q < 8; ++q) {
            const float g = -__logf(-__logf(uu[q] + 1e-20f) + 1e-20f);
            pm[q] = sL[row * 128 + tx * 8 + q] + b2v[q] + g;
        }
        float mx = pm[0];
#pragma unroll
        for (int q = 1; q < 8; ++q) mx = fmaxf(mx, pm[q]);
        for (int d = 1; d < 16; d <<= 1) mx = fmaxf(mx, __shfl_xor(mx, d, 16));
        float se = 0.0f;
#pragma unroll
        for (int q = 0; q < 8; ++q) { pr[i][q] = __expf(pm[q] - mx); se += pr[i][q]; }
        for (int d = 1; d < 16; d <<= 1) se += __shfl_xor(se, d, 16);
        const float inv = 1.0f / se;
#pragma unroll
        for (int q = 0; q < 8; ++q) pr[i][q] *= inv;
        pmaxv[i] = inv;   // max prob == exp(0)*inv exactly
    }

    // ---- top-K threshold: bisection + exact extraction (group of 16 lanes) ----
    float thr_[2];
#pragma unroll
    for (int i = 0; i < 2; ++i) {
        // invariant: cnt_gt(lo) >= 30 (lo=0: all 128 probs > 0), cnt_gt(hi) <= 29
        float lo = 0.0f;
        float hi = fminf(pmaxv[i], 1.0f / 30.0f);
        for (int it = 0; it < 24; ++it) {
            const float mid = 0.5f * (lo + hi);
            int cnt = 0;
#pragma unroll
            for (int q = 0; q < 8; ++q) cnt += (pr[i][q] > mid) ? 1 : 0;
            for (int d = 1; d < 16; d <<= 1) cnt += __shfl_xor(cnt, d, 16);
            const bool ge = (cnt >= TOPK);
            lo = ge ? mid : lo;
            hi = ge ? hi : mid;
        }
        // exact: count strictly above hi, then extract down to rank 30
        int cnt = 0;
#pragma unroll
        for (int q = 0; q < 8; ++q) cnt += (pr[i][q] > hi) ? 1 : 0;
        for (int d = 1; d < 16; d <<= 1) cnt += __shfl_xor(cnt, d, 16);

        int rep = TOPK - cnt;     // >= 1
        float t = hi, T = hi;
        bool leq = true;          // first pass: values <= hi; later: < t
        for (int guard = 0; guard < 32 && rep > 0; ++guard) {
            float m = -1.0f;
#pragma unroll
            for (int q = 0; q < 8; ++q) {
                const float v = pr[i][q];
                const bool in = leq ? (v <= t) : (v < t);
                m = fmaxf(m, in ? v : -1.0f);
            }
            for (int d = 1; d < 16; d <<= 1) m = fmaxf(m, __shfl_xor(m, d, 16));
            int ce = 0;
#pragma unroll
            for (int q = 0; q < 8; ++q) ce += (pr[i][q] == m) ? 1 : 0;
            for (int d = 1; d < 16; d <<= 1) ce += __shfl_xor(ce, d, 16);
            T = m;
            if (ce == 0) break;   // safety (degenerate)
            rep -= ce;
            t = m;
            leq = false;
        }
        thr_[i] = T;
    }

    // ---- sigmoid gate + mask + store ----
#pragma unroll
    for (int i = 0; i < 2; ++i) {
        const int s = s0 + ty * 2 + i;
        if (s < SS) {
            const float mz = (mask[(size_t)c * LL + s + 1] != 0) ? 0.0f : 1.0f;
            float ov[8];
#pragma unroll
            for (int q = 0; q < 8; ++q) {
                const float sm = 1.0f / (1.0f + __expf((thr_[i] - pr[i][q]) * 100.0f));
                ov[q] = pr[i][q] * sm * mz;
            }
            float* op = out + ((size_t)c * SS + s) * MM + tx * 8;
            float4 o0, o1;
            o0.x=ov[0]; o0.y=ov[1]; o0.z=ov[2]; o0.w=ov[3];
            o1.x=ov[4]; o1.y=ov[5]; o1.z=ov[6]; o1.w=ov[7];
            *(float4*)(op + 0) = o0;
            *(float4*)(op + 4) = o1;
        }
    }

    if (tid < 32) {
        const int s = s0 + tid;
        if (s < SS)
            outk[(size_t)c * SS + s] = (mask[(size_t)c * LL + s + 1] != 0) ? 1.0f : 0.0f;
    }
}

extern "C" void kernel_launch(void* const* d_in, const int* in_sizes, int n_in,
                              void* d_out, int out_size, void* d_ws, size_t ws_size,
                              hipStream_t stream) {
    const float* x     = (const float*)d_in[0];
    const int*   mask  = (const int*)d_in[1];
    const float* noise = (const float*)d_in[2];
    const float* W1    = (const float*)d_in[3];
    const float* b1    = (const float*)d_in[4];
    const float* W2    = (const float*)d_in[5];
    const float* b2    = (const float*)d_in[6];
    float* out  = (float*)d_out;
    float* outk = out + (size_t)CC * SS * MM;

    unsigned short* W1T = (unsigned short*)d_ws;            // 256 x 512 bf16 = 256 KB
    unsigned short* W2T = W1T + (size_t)HH * EE;            // 128 x 256 bf16 =  64 KB

    prep_weights<<<dim3(80), dim3(256), 0, stream>>>(W1, W2, W1T, W2T);

    dim3 grid(256, CC);   // 256 blocks x 32 rows = 8192 >= 8191
    gene_router_kernel<<<grid, dim3(256), 0, stream>>>(x, mask, noise, W1T, b1, W2T, b2, out, outk);
}